// Round 12
// baseline (60.581 us; speedup 1.0000x reference)
//
#include <hip/hip_runtime.h>
#include <hip/hip_bf16.h>

#define HH 512
#define WW 512
#define HWSZ (512*512)

typedef _Float16 hh4 __attribute__((ext_vector_type(4)));
typedef _Float16 hh2 __attribute__((ext_vector_type(2)));
typedef float    ff4 __attribute__((ext_vector_type(4)));

constexpr int TW = 32, TH = 32;   // output tile
constexpr int SW = 56;            // staged cols bx0-12 .. bx0+43
constexpr int SH = 52;            // staged rows by0-10 .. by0+41
constexpr int LP = 60;            // stride %4==0 (b64 rp quads + b128 pairs aligned)
constexpr int NG = SW / 4;        // 14 groups of 4 px
constexpr int NSLOT = SH * NG;    // 728
constexpr int NIT = 6;            // 6*128 >= 728 (tail clamped)

__device__ __forceinline__ float clamp01(float x) {
    return __builtin_amdgcn_fmed3f(x, 0.0f, 1.0f);
}
__device__ __forceinline__ hh2 clamp01h2(hh2 x) {
    const hh2 z = {(_Float16)0.0f, (_Float16)0.0f};
    const hh2 o = {(_Float16)1.0f, (_Float16)1.0f};
    return __builtin_elementwise_min(__builtin_elementwise_max(x, z), o);
}
__device__ __forceinline__ hh2 pkrtz(float a, float b) {
    return __builtin_bit_cast(hh2, __builtin_amdgcn_cvt_pkrtz(a, b));
}

__global__ __launch_bounds__(128, 2)
void mlr_fused_kernel(const float* __restrict__ rgbad,
                      const float* __restrict__ lens_eff,
                      const float* __restrict__ focal,
                      float* __restrict__ out,
                      int nbx, int B)
{
    __shared__ uint2 sP[SH * LP];       // half4 {r*pa,g*pa,b*pa,pa}  25.0 KB
    __shared__ uint  rP[SH * LP / 2];   // half2 rp05 pairs            6.2 KB
    __shared__ int   maxbits;

    const int tx  = threadIdx.x;    // 0..7  (4 px each)
    const int ty  = threadIdx.y;    // 0..15 (2 output rows each)
    const int tid = ty * 8 + tx;
    const int bid = blockIdx.x;     // batch-interleaved 1D grid
    const int bb  = bid % B;
    const int t   = bid / B;
    const int bx0 = (t % nbx) * TW;
    const int by0 = (t / nbx) * TH;
    const float lens = lens_eff[bb];

    static constexpr float DJ[44] = {
        0.f, 1.f, 1.41421356f, 2.f, 2.23606798f, 2.82842712f, 3.f, 3.16227766f,
        3.60555128f, 4.f, 4.12310563f, 4.24264069f, 4.47213595f, 5.f, 5.09901951f,
        5.38516481f, 5.65685425f, 5.83095189f, 6.f, 6.08276253f, 6.32455532f,
        6.40312424f, 6.70820393f, 7.f, 7.07106781f, 7.21110255f, 7.28010989f,
        7.61577311f, 7.81024968f, 8.f, 8.06225775f, 8.24621125f, 8.48528137f,
        8.54400375f, 8.60232527f, 8.94427191f, 9.f, 9.05538514f, 9.21954446f,
        9.43398113f, 9.48683298f, 9.84885780f, 9.89949494f, 10.f };
    static constexpr float CNT[44] = {
        1,4,4,4,8,4,4,8,8,4,8,4,8,12,8,8,4,8,4,8,8,8,
        8,4,12,8,8,8,8,4,16,8,4,8,8,8,4,8,16,8,8,8,4,12 };

    // per-thread: 2 output rows x 4 px
    float blR[2][4] = {{0,0,0,0},{0,0,0,0}};
    float blG[2][4] = {{0,0,0,0},{0,0,0,0}};
    float blB[2][4] = {{0,0,0,0},{0,0,0,0}};
    float trans[2][4] = {{1,1,1,1},{1,1,1,1}};

#pragma unroll 1
    for (int l = 0; l < 3; ++l) {
        __syncthreads();                 // previous layer fully consumed
        if (tid == 0) maxbits = 0;
        __syncthreads();

        const float* pin = rgbad + (size_t)(bb * 15 + 5 * l) * HWSZ;
        const float* pfo = focal + (size_t)(bb * 15 + 5 * l) * HWSZ;
        float mloc = 0.f;

        // ---- staging: fixed-trip loop, float4 loads (tail clamped, benign) ----
#pragma unroll
        for (int it = 0; it < NIT; ++it) {
            int s = tid + it * 128;
            s = (s < NSLOT) ? s : (NSLOT - 1);
            const int row = s / NG;
            const int grp = s - row * NG;
            const int gy  = by0 - 10 + row;
            const int gx0 = bx0 - 12 + 4 * grp;     // %4 == 0

            ff4 i0 = {0,0,0,0}, i1 = {0,0,0,0}, i2 = {0,0,0,0}, i3 = {0,0,0,0}, i4 = {0,0,0,0};
            ff4 f0 = {0,0,0,0}, f1 = {0,0,0,0}, f2 = {0,0,0,0}, f3 = {0,0,0,0}, f4 = {0,0,0,0};
            const bool valid = ((unsigned)gy < (unsigned)HH) && ((unsigned)gx0 < (unsigned)WW);
            if (valid) {
                const size_t off = (size_t)gy * WW + (size_t)gx0;
                i0 = *reinterpret_cast<const ff4*>(pin + off);
                i1 = *reinterpret_cast<const ff4*>(pin + off +   HWSZ);
                i2 = *reinterpret_cast<const ff4*>(pin + off + 2*HWSZ);
                i3 = *reinterpret_cast<const ff4*>(pin + off + 3*HWSZ);
                i4 = *reinterpret_cast<const ff4*>(pin + off + 4*HWSZ);
                f0 = *reinterpret_cast<const ff4*>(pfo + off);
                f1 = *reinterpret_cast<const ff4*>(pfo + off +   HWSZ);
                f2 = *reinterpret_cast<const ff4*>(pfo + off + 2*HWSZ);
                f3 = *reinterpret_cast<const ff4*>(pfo + off + 3*HWSZ);
                f4 = *reinterpret_cast<const ff4*>(pfo + off + 4*HWSZ);
            }
            uint2 pk[4];
            unsigned short rh[4];
#pragma unroll
            for (int k = 0; k < 4; ++k) {
                const float cr = i0[k] - f0[k];
                const float cg = i1[k] - f1[k];
                const float cb = i2[k] - f2[k];
                const float ca = i3[k] - f3[k];
                const float cd = i4[k] - f4[k];
                const float r  = fminf(fabsf(cd) * lens, 10.f);
                const float rp05 = r + 0.5f;
                const hh2 rp2s = pkrtz(rp05, rp05);
                float aacc = 0.f;
#pragma unroll
                for (int j = 0; j < 44; j += 2) {
                    const hh2 dj2 = {(_Float16)DJ[j], (_Float16)DJ[j + 1]};
                    const hh2 c2  = {(_Float16)CNT[j], (_Float16)CNT[j + 1]};
                    const hh2 w2  = clamp01h2(rp2s - dj2);
                    aacc = __builtin_amdgcn_fdot2(w2, c2, aacc, false);
                }
                const float inv = 1.0f / (aacc + 1e-8f);
                const float pa  = ca * inv;          // 0 when OOB (loads were 0)
                hh4 hv;
                hv.x = (_Float16)(cr * pa);
                hv.y = (_Float16)(cg * pa);
                hv.z = (_Float16)(cb * pa);
                hv.w = (_Float16)pa;
                pk[k] = __builtin_bit_cast(uint2, hv);
                rh[k] = __builtin_bit_cast(unsigned short, (_Float16)rp05);
                mloc  = fmaxf(mloc, rp05);           // 0.5 for OOB px: harmless
            }
            const int base = row * LP + 4 * grp;     // %4 == 0
            uint4 s01, s23;
            s01.x = pk[0].x; s01.y = pk[0].y; s01.z = pk[1].x; s01.w = pk[1].y;
            s23.x = pk[2].x; s23.y = pk[2].y; s23.z = pk[3].x; s23.w = pk[3].y;
            *reinterpret_cast<uint4*>(&sP[base])     = s01;
            *reinterpret_cast<uint4*>(&sP[base + 2]) = s23;
            uint2 rr2;
            rr2.x = (uint)rh[0] | ((uint)rh[1] << 16);
            rr2.y = (uint)rh[2] | ((uint)rh[3] << 16);
            *reinterpret_cast<uint2*>(&rP[base >> 1]) = rr2;
        }
        atomicMax(&maxbits, __float_as_int(mloc));
        __syncthreads();

        const float rmax = __int_as_float(maxbits);   // block-uniform
        const int U = min(10, (int)ceilf(rmax) - 1);
        const int auMax = min(11, U + 1);

        float aR[2][4] = {{0,0,0,0},{0,0,0,0}};
        float aG[2][4] = {{0,0,0,0},{0,0,0,0}};
        float aB[2][4] = {{0,0,0,0},{0,0,0,0}};
        float aW[2][4] = {{0,0,0,0},{0,0,0,0}};

        // packed dd tables: T[m] = {d(m-13), d(m-12)} for a given |u|
        hh2 T0[26], T1[26];
#define BUILD_T(T_, U2F_) { \
            _Pragma("unroll") \
            for (int m = 0; m < 26; ++m) { \
                const int dxa = m - 13, dxb = m - 12; \
                const float qa = (U2F_) + (float)(dxa * dxa); \
                const float qb = (U2F_) + (float)(dxb * dxb); \
                const float da = (qa <= 100.0f) ? __builtin_sqrtf(qa) : 3000.0f; \
                const float db = (qb <= 100.0f) ? __builtin_sqrtf(qb) : 3000.0f; \
                T_[m] = pkrtz(da, db); \
            } }

        BUILD_T(T0, 0.0f)          // T(au-1) for au=1

        // one source pair applied to both output rows; TA_/TB_ = dd tables
        // for row0 / row1 respectively
#define PCOMP2(SP_, RPH_, v0, TA_, TB_) { \
            const hh2 rp2 = __builtin_bit_cast(hh2, (RPH_)); \
            const hh2 cR = __builtin_bit_cast(hh2, __builtin_amdgcn_perm((SP_).z, (SP_).x, 0x05040100u)); \
            const hh2 cG = __builtin_bit_cast(hh2, __builtin_amdgcn_perm((SP_).z, (SP_).x, 0x07060302u)); \
            const hh2 cB = __builtin_bit_cast(hh2, __builtin_amdgcn_perm((SP_).w, (SP_).y, 0x05040100u)); \
            const hh2 cA = __builtin_bit_cast(hh2, __builtin_amdgcn_perm((SP_).w, (SP_).y, 0x07060302u)); \
            _Pragma("unroll") \
            for (int ox = 0; ox < 4; ++ox) { \
                const hh2 w0 = clamp01h2(rp2 - TA_[(v0) - ox + 13]); \
                aR[0][ox] = __builtin_amdgcn_fdot2(cR, w0, aR[0][ox], false); \
                aG[0][ox] = __builtin_amdgcn_fdot2(cG, w0, aG[0][ox], false); \
                aB[0][ox] = __builtin_amdgcn_fdot2(cB, w0, aB[0][ox], false); \
                aW[0][ox] = __builtin_amdgcn_fdot2(cA, w0, aW[0][ox], false); \
                const hh2 w1 = clamp01h2(rp2 - TB_[(v0) - ox + 13]); \
                aR[1][ox] = __builtin_amdgcn_fdot2(cR, w1, aR[1][ox], false); \
                aG[1][ox] = __builtin_amdgcn_fdot2(cG, w1, aG[1][ox], false); \
                aB[1][ox] = __builtin_amdgcn_fdot2(cB, w1, aB[1][ox], false); \
                aW[1][ox] = __builtin_amdgcn_fdot2(cA, w1, aW[1][ox], false); \
            } }
#define LDQ(nm, rb, off)   const uint2 nm = *reinterpret_cast<const uint2*>(&rP[((rb) + (off)) >> 1]);
#define LD128(nm, rb, off) const uint4 nm = *reinterpret_cast<const uint4*>(&sP[(rb) + (off)]);

        // source rows c = au (u0=au, u1=au-1) and c = 1-au (u0=au-1*, u1=au)
        // (*by |.|). Tables: row au -> (T1, T0); row 1-au -> (T0, T1).
#pragma unroll 1
        for (int au = 1; au <= auMax; ++au) {
            const float au1 = (float)(au - 1);
            const float vm2 = rmax * rmax - au1 * au1;  // conservative dx^2 bound
            BUILD_T(T1, (float)(au * au))

            const int rbA = (2 * ty + 10 + au)     * LP + 12 + 4 * tx;  // row c=au
            const int rbB = (2 * ty + 10 + 1 - au) * LP + 12 + 4 * tx;  // row c=1-au

            // core |dx|<=2-ish: pairs v0 = -2,0,2,4
            LDQ(qAm4, rbA, -4) LDQ(qA0, rbA, 0) LDQ(qA4, rbA, 4)
            LD128(sAm2, rbA, -2) LD128(sA0, rbA, 0) LD128(sA2, rbA, 2) LD128(sA4, rbA, 4)
            LDQ(qBm4, rbB, -4) LDQ(qB0, rbB, 0) LDQ(qB4, rbB, 4)
            LD128(sBm2, rbB, -2) LD128(sB0, rbB, 0) LD128(sB2, rbB, 2) LD128(sB4, rbB, 4)
            PCOMP2(sAm2, qAm4.y, -2, T1, T0) PCOMP2(sA0, qA0.x, 0, T1, T0)
            PCOMP2(sA2,  qA0.y,  2, T1, T0) PCOMP2(sA4, qA4.x, 4, T1, T0)
            PCOMP2(sBm2, qBm4.y, -2, T0, T1) PCOMP2(sB0, qB0.x, 0, T0, T1)
            PCOMP2(sB2,  qB0.y,  2, T0, T1) PCOMP2(sB4, qB4.x, 4, T0, T1)
            if (vm2 > 9.0f) {
                LDQ(qAm8, rbA, -8) LDQ(qA8, rbA, 8)
                LD128(sAm6, rbA, -6) LD128(sAm4, rbA, -4) LD128(sA6, rbA, 6) LD128(sA8, rbA, 8)
                LDQ(qBm8, rbB, -8) LDQ(qB8, rbB, 8)
                LD128(sBm6, rbB, -6) LD128(sBm4, rbB, -4) LD128(sB6, rbB, 6) LD128(sB8, rbB, 8)
                PCOMP2(sAm6, qAm8.y, -6, T1, T0) PCOMP2(sAm4, qAm4.x, -4, T1, T0)
                PCOMP2(sA6,  qA4.y,  6, T1, T0) PCOMP2(sA8,  qA8.x,  8, T1, T0)
                PCOMP2(sBm6, qBm8.y, -6, T0, T1) PCOMP2(sBm4, qBm4.x, -4, T0, T1)
                PCOMP2(sB6,  qB4.y,  6, T0, T1) PCOMP2(sB8,  qB8.x,  8, T0, T1)
                if (vm2 > 36.0f) {
                    LD128(sAm8, rbA, -8) LD128(sA10, rbA, 10)
                    LD128(sBm8, rbB, -8) LD128(sB10, rbB, 10)
                    PCOMP2(sAm8, qAm8.x, -8, T1, T0) PCOMP2(sA10, qA8.y, 10, T1, T0)
                    PCOMP2(sBm8, qBm8.x, -8, T0, T1) PCOMP2(sB10, qB8.y, 10, T0, T1)
                    if (vm2 > 81.0f) {
                        LDQ(qAm12, rbA, -12) LDQ(qA12, rbA, 12)
                        LD128(sAm10, rbA, -10) LD128(sA12, rbA, 12)
                        LDQ(qBm12, rbB, -12) LDQ(qB12, rbB, 12)
                        LD128(sBm10, rbB, -10) LD128(sB12, rbB, 12)
                        PCOMP2(sAm10, qAm12.y, -10, T1, T0) PCOMP2(sA12, qA12.x, 12, T1, T0)
                        PCOMP2(sBm10, qBm12.y, -10, T0, T1) PCOMP2(sB12, qB12.x, 12, T0, T1)
                    }
                }
            }
            // T0 <- T1 for next au
#pragma unroll
            for (int m = 0; m < 26; ++m) T0[m] = T1[m];
        }
#undef PCOMP2
#undef LDQ
#undef LD128
#undef BUILD_T

        // front-to-back compositing, both rows
#pragma unroll
        for (int rr = 0; rr < 2; ++rr) {
#pragma unroll
            for (int ox = 0; ox < 4; ++ox) {
                const float wsum = aW[rr][ox];
                const float occ  = clamp01(wsum);
                const float f    = trans[rr][ox] * occ / (wsum + 1e-8f);
                blR[rr][ox] = fmaf(aR[rr][ox], f, blR[rr][ox]);
                blG[rr][ox] = fmaf(aG[rr][ox], f, blG[rr][ox]);
                blB[rr][ox] = fmaf(aB[rr][ox], f, blB[rr][ox]);
                trans[rr][ox] *= (1.0f - occ);
            }
        }
    }

#pragma unroll
    for (int rr = 0; rr < 2; ++rr) {
        const int oy = by0 + 2 * ty + rr;
        const size_t obase = (size_t)bb * 3 * HWSZ + (size_t)oy * WW + (size_t)(bx0 + 4 * tx);
        float4 vR, vG, vB;
        vR.x = blR[rr][0]; vR.y = blR[rr][1]; vR.z = blR[rr][2]; vR.w = blR[rr][3];
        vG.x = blG[rr][0]; vG.y = blG[rr][1]; vG.z = blG[rr][2]; vG.w = blG[rr][3];
        vB.x = blB[rr][0]; vB.y = blB[rr][1]; vB.z = blB[rr][2]; vB.w = blB[rr][3];
        *reinterpret_cast<float4*>(out + obase)            = vR;
        *reinterpret_cast<float4*>(out + obase + HWSZ)     = vG;
        *reinterpret_cast<float4*>(out + obase + 2 * HWSZ) = vB;
    }
}

extern "C" void kernel_launch(void* const* d_in, const int* in_sizes, int n_in,
                              void* d_out, int out_size, void* d_ws, size_t ws_size,
                              hipStream_t stream) {
    const float* rgbad = (const float*)d_in[0];
    const float* lens  = (const float*)d_in[1];
    const float* focal = (const float*)d_in[2];
    float* out = (float*)d_out;
    const int B = in_sizes[1];                 // lens_effect: [B,1]
    const int nbx = WW / TW;                   // 16
    const int nby = HH / TH;                   // 16
    dim3 grid(nbx * nby * B, 1, 1);            // 512 blocks, batch-interleaved
    dim3 block(8, 16, 1);                      // 128 threads: 4px x 2rows each
    hipLaunchKernelGGL(mlr_fused_kernel, grid, block, 0, stream,
                       rgbad, lens, focal, out, nbx, B);
}

// Round 13
// 59.091 us; speedup vs baseline: 1.0252x; 1.0252x over previous
//
#include <hip/hip_runtime.h>
#include <hip/hip_bf16.h>

#define HH 512
#define WW 512
#define HWSZ (512*512)

typedef _Float16 hh4 __attribute__((ext_vector_type(4)));
typedef _Float16 hh2 __attribute__((ext_vector_type(2)));
typedef float    ff4 __attribute__((ext_vector_type(4)));

constexpr int TW = 64, TH = 16;   // output tile
constexpr int SW = 88;            // staged cols bx0-12 .. bx0+75
constexpr int SH = 36;            // staged rows by0-10 .. by0+25
constexpr int LP = 92;            // stride %4==0 (b64 quads + b128 pairs aligned)
constexpr int NG = SW / 4;        // 22 groups of 4 px
constexpr int NSLOT = SH * NG;    // 792
constexpr int NIT = 7;            // 7*128 >= 792 (tail clamped)

__device__ __forceinline__ float clamp01(float x) {
    return __builtin_amdgcn_fmed3f(x, 0.0f, 1.0f);
}
__device__ __forceinline__ hh2 clamp01h2(hh2 x) {
    const hh2 z = {(_Float16)0.0f, (_Float16)0.0f};
    const hh2 o = {(_Float16)1.0f, (_Float16)1.0f};
    return __builtin_elementwise_min(__builtin_elementwise_max(x, z), o);
}
__device__ __forceinline__ hh2 pkrtz(float a, float b) {
    return __builtin_bit_cast(hh2, __builtin_amdgcn_cvt_pkrtz(a, b));
}

// ---------------------------------------------------------------------------
// Kernel 1: ONE (batch, layer) scatter per block-slice; 2 output rows/thread
// (halves LDS gather traffic); writes fp16x4 {R,G,B,W} partials to ws.
// grid = ntiles * 3B blocks -> 3 waves/SIMD chip-wide (fixes R12's 1/SIMD).
// ---------------------------------------------------------------------------
__global__ __launch_bounds__(128, 2)
void mlr_layer_kernel(const float* __restrict__ rgbad,
                      const float* __restrict__ lens_eff,
                      const float* __restrict__ focal,
                      uint2* __restrict__ ws,
                      int nbx, int B)
{
    __shared__ uint2 sP[SH * LP];       // half4 {r*pa,g*pa,b*pa,pa}  26.5 KB
    __shared__ uint  rP[SH * LP / 2];   // half2 rp05 pairs            6.6 KB
    __shared__ int   maxbits;

    const int tx  = threadIdx.x;    // 0..15 (4 px each)
    const int ty  = threadIdx.y;    // 0..7  (2 output rows each)
    const int tid = ty * 16 + tx;
    const int nsl = 3 * B;          // slices per tile (batch fastest -> balance)
    const int bid = blockIdx.x;
    const int sl  = bid % nsl;
    const int bb  = sl % B;
    const int l   = sl / B;
    const int t   = bid / nsl;
    const int bx0 = (t % nbx) * TW;
    const int by0 = (t / nbx) * TH;
    const float lens = lens_eff[bb];

    static constexpr float DJ[44] = {
        0.f, 1.f, 1.41421356f, 2.f, 2.23606798f, 2.82842712f, 3.f, 3.16227766f,
        3.60555128f, 4.f, 4.12310563f, 4.24264069f, 4.47213595f, 5.f, 5.09901951f,
        5.38516481f, 5.65685425f, 5.83095189f, 6.f, 6.08276253f, 6.32455532f,
        6.40312424f, 6.70820393f, 7.f, 7.07106781f, 7.21110255f, 7.28010989f,
        7.61577311f, 7.81024968f, 8.f, 8.06225775f, 8.24621125f, 8.48528137f,
        8.54400375f, 8.60232527f, 8.94427191f, 9.f, 9.05538514f, 9.21954446f,
        9.43398113f, 9.48683298f, 9.84885780f, 9.89949494f, 10.f };
    static constexpr float CNT[44] = {
        1,4,4,4,8,4,4,8,8,4,8,4,8,12,8,8,4,8,4,8,8,8,
        8,4,12,8,8,8,8,4,16,8,4,8,8,8,4,8,16,8,8,8,4,12 };

    if (tid == 0) maxbits = 0;
    __syncthreads();

    const float* pin = rgbad + (size_t)(bb * 15 + 5 * l) * HWSZ;
    const float* pfo = focal + (size_t)(bb * 15 + 5 * l) * HWSZ;
    float mloc = 0.f;

    // ---- staging: fixed-trip loop, float4 loads (tail clamped, benign) ----
#pragma unroll
    for (int it = 0; it < NIT; ++it) {
        int s = tid + it * 128;
        s = (s < NSLOT) ? s : (NSLOT - 1);
        const int row = s / NG;
        const int grp = s - row * NG;
        const int gy  = by0 - 10 + row;
        const int gx0 = bx0 - 12 + 4 * grp;     // %4 == 0

        ff4 i0 = {0,0,0,0}, i1 = {0,0,0,0}, i2 = {0,0,0,0}, i3 = {0,0,0,0}, i4 = {0,0,0,0};
        ff4 f0 = {0,0,0,0}, f1 = {0,0,0,0}, f2 = {0,0,0,0}, f3 = {0,0,0,0}, f4 = {0,0,0,0};
        const bool valid = ((unsigned)gy < (unsigned)HH) && ((unsigned)gx0 < (unsigned)WW);
        if (valid) {
            const size_t off = (size_t)gy * WW + (size_t)gx0;
            i0 = *reinterpret_cast<const ff4*>(pin + off);
            i1 = *reinterpret_cast<const ff4*>(pin + off +   HWSZ);
            i2 = *reinterpret_cast<const ff4*>(pin + off + 2*HWSZ);
            i3 = *reinterpret_cast<const ff4*>(pin + off + 3*HWSZ);
            i4 = *reinterpret_cast<const ff4*>(pin + off + 4*HWSZ);
            f0 = *reinterpret_cast<const ff4*>(pfo + off);
            f1 = *reinterpret_cast<const ff4*>(pfo + off +   HWSZ);
            f2 = *reinterpret_cast<const ff4*>(pfo + off + 2*HWSZ);
            f3 = *reinterpret_cast<const ff4*>(pfo + off + 3*HWSZ);
            f4 = *reinterpret_cast<const ff4*>(pfo + off + 4*HWSZ);
        }
        uint2 pk[4];
        unsigned short rh[4];
#pragma unroll
        for (int k = 0; k < 4; ++k) {
            const float cr = i0[k] - f0[k];
            const float cg = i1[k] - f1[k];
            const float cb = i2[k] - f2[k];
            const float ca = i3[k] - f3[k];
            const float cd = i4[k] - f4[k];
            const float r  = fminf(fabsf(cd) * lens, 10.f);
            const float rp05 = r + 0.5f;
            const hh2 rp2s = pkrtz(rp05, rp05);
            float aacc = 0.f;
#pragma unroll
            for (int j = 0; j < 44; j += 2) {
                const hh2 dj2 = {(_Float16)DJ[j], (_Float16)DJ[j + 1]};
                const hh2 c2  = {(_Float16)CNT[j], (_Float16)CNT[j + 1]};
                const hh2 w2  = clamp01h2(rp2s - dj2);
                aacc = __builtin_amdgcn_fdot2(w2, c2, aacc, false);
            }
            const float inv = 1.0f / (aacc + 1e-8f);
            const float pa  = ca * inv;          // 0 when OOB (loads were 0)
            hh4 hv;
            hv.x = (_Float16)(cr * pa);
            hv.y = (_Float16)(cg * pa);
            hv.z = (_Float16)(cb * pa);
            hv.w = (_Float16)pa;
            pk[k] = __builtin_bit_cast(uint2, hv);
            rh[k] = __builtin_bit_cast(unsigned short, (_Float16)rp05);
            mloc  = fmaxf(mloc, rp05);           // 0.5 for OOB px: harmless
        }
        const int base = row * LP + 4 * grp;     // %4 == 0
        uint4 s01, s23;
        s01.x = pk[0].x; s01.y = pk[0].y; s01.z = pk[1].x; s01.w = pk[1].y;
        s23.x = pk[2].x; s23.y = pk[2].y; s23.z = pk[3].x; s23.w = pk[3].y;
        *reinterpret_cast<uint4*>(&sP[base])     = s01;
        *reinterpret_cast<uint4*>(&sP[base + 2]) = s23;
        uint2 rr2;
        rr2.x = (uint)rh[0] | ((uint)rh[1] << 16);
        rr2.y = (uint)rh[2] | ((uint)rh[3] << 16);
        *reinterpret_cast<uint2*>(&rP[base >> 1]) = rr2;
    }
    atomicMax(&maxbits, __float_as_int(mloc));
    __syncthreads();

    const float rmax = __int_as_float(maxbits);   // block-uniform
    const int U = min(10, (int)ceilf(rmax) - 1);
    const int auMax = min(11, U + 1);

    float aR[2][4] = {{0,0,0,0},{0,0,0,0}};
    float aG[2][4] = {{0,0,0,0},{0,0,0,0}};
    float aB[2][4] = {{0,0,0,0},{0,0,0,0}};
    float aW[2][4] = {{0,0,0,0},{0,0,0,0}};

    hh2 T0[26], T1[26];
#define BUILD_T(T_, U2F_) { \
        _Pragma("unroll") \
        for (int m = 0; m < 26; ++m) { \
            const int dxa = m - 13, dxb = m - 12; \
            const float qa = (U2F_) + (float)(dxa * dxa); \
            const float qb = (U2F_) + (float)(dxb * dxb); \
            const float da = (qa <= 100.0f) ? __builtin_sqrtf(qa) : 3000.0f; \
            const float db = (qb <= 100.0f) ? __builtin_sqrtf(qb) : 3000.0f; \
            T_[m] = pkrtz(da, db); \
        } }

    BUILD_T(T0, 0.0f)

    // one source pair applied to both output rows (TA_/TB_ = dd for row0/row1)
#define PCOMP2(SP_, RPH_, v0, TA_, TB_) { \
        const hh2 rp2 = __builtin_bit_cast(hh2, (RPH_)); \
        const hh2 cR = __builtin_bit_cast(hh2, __builtin_amdgcn_perm((SP_).z, (SP_).x, 0x05040100u)); \
        const hh2 cG = __builtin_bit_cast(hh2, __builtin_amdgcn_perm((SP_).z, (SP_).x, 0x07060302u)); \
        const hh2 cB = __builtin_bit_cast(hh2, __builtin_amdgcn_perm((SP_).w, (SP_).y, 0x05040100u)); \
        const hh2 cA = __builtin_bit_cast(hh2, __builtin_amdgcn_perm((SP_).w, (SP_).y, 0x07060302u)); \
        _Pragma("unroll") \
        for (int ox = 0; ox < 4; ++ox) { \
            const hh2 w0 = clamp01h2(rp2 - TA_[(v0) - ox + 13]); \
            aR[0][ox] = __builtin_amdgcn_fdot2(cR, w0, aR[0][ox], false); \
            aG[0][ox] = __builtin_amdgcn_fdot2(cG, w0, aG[0][ox], false); \
            aB[0][ox] = __builtin_amdgcn_fdot2(cB, w0, aB[0][ox], false); \
            aW[0][ox] = __builtin_amdgcn_fdot2(cA, w0, aW[0][ox], false); \
            const hh2 w1 = clamp01h2(rp2 - TB_[(v0) - ox + 13]); \
            aR[1][ox] = __builtin_amdgcn_fdot2(cR, w1, aR[1][ox], false); \
            aG[1][ox] = __builtin_amdgcn_fdot2(cG, w1, aG[1][ox], false); \
            aB[1][ox] = __builtin_amdgcn_fdot2(cB, w1, aB[1][ox], false); \
            aW[1][ox] = __builtin_amdgcn_fdot2(cA, w1, aW[1][ox], false); \
        } }
#define LDQ(nm, rb, off)   const uint2 nm = *reinterpret_cast<const uint2*>(&rP[((rb) + (off)) >> 1]);
#define LD128(nm, rb, off) const uint4 nm = *reinterpret_cast<const uint4*>(&sP[(rb) + (off)]);

    // source rows c = row0+au (tables T1,T0) and c = row0+1-au (tables T0,T1)
#pragma unroll 1
    for (int au = 1; au <= auMax; ++au) {
        const float au1 = (float)(au - 1);
        const float vm2 = rmax * rmax - au1 * au1;  // conservative dx^2 bound
        BUILD_T(T1, (float)(au * au))

        const int rbA = (2 * ty + 10 + au)     * LP + 12 + 4 * tx;
        const int rbB = (2 * ty + 10 + 1 - au) * LP + 12 + 4 * tx;

        LDQ(qAm4, rbA, -4) LDQ(qA0, rbA, 0) LDQ(qA4, rbA, 4)
        LD128(sAm2, rbA, -2) LD128(sA0, rbA, 0) LD128(sA2, rbA, 2) LD128(sA4, rbA, 4)
        LDQ(qBm4, rbB, -4) LDQ(qB0, rbB, 0) LDQ(qB4, rbB, 4)
        LD128(sBm2, rbB, -2) LD128(sB0, rbB, 0) LD128(sB2, rbB, 2) LD128(sB4, rbB, 4)
        PCOMP2(sAm2, qAm4.y, -2, T1, T0) PCOMP2(sA0, qA0.x, 0, T1, T0)
        PCOMP2(sA2,  qA0.y,  2, T1, T0) PCOMP2(sA4, qA4.x, 4, T1, T0)
        PCOMP2(sBm2, qBm4.y, -2, T0, T1) PCOMP2(sB0, qB0.x, 0, T0, T1)
        PCOMP2(sB2,  qB0.y,  2, T0, T1) PCOMP2(sB4, qB4.x, 4, T0, T1)
        if (vm2 > 9.0f) {
            LDQ(qAm8, rbA, -8) LDQ(qA8, rbA, 8)
            LD128(sAm6, rbA, -6) LD128(sAm4, rbA, -4) LD128(sA6, rbA, 6) LD128(sA8, rbA, 8)
            LDQ(qBm8, rbB, -8) LDQ(qB8, rbB, 8)
            LD128(sBm6, rbB, -6) LD128(sBm4, rbB, -4) LD128(sB6, rbB, 6) LD128(sB8, rbB, 8)
            PCOMP2(sAm6, qAm8.y, -6, T1, T0) PCOMP2(sAm4, qAm4.x, -4, T1, T0)
            PCOMP2(sA6,  qA4.y,  6, T1, T0) PCOMP2(sA8,  qA8.x,  8, T1, T0)
            PCOMP2(sBm6, qBm8.y, -6, T0, T1) PCOMP2(sBm4, qBm4.x, -4, T0, T1)
            PCOMP2(sB6,  qB4.y,  6, T0, T1) PCOMP2(sB8,  qB8.x,  8, T0, T1)
            if (vm2 > 36.0f) {
                LD128(sAm8, rbA, -8) LD128(sA10, rbA, 10)
                LD128(sBm8, rbB, -8) LD128(sB10, rbB, 10)
                PCOMP2(sAm8, qAm8.x, -8, T1, T0) PCOMP2(sA10, qA8.y, 10, T1, T0)
                PCOMP2(sBm8, qBm8.x, -8, T0, T1) PCOMP2(sB10, qB8.y, 10, T0, T1)
                if (vm2 > 81.0f) {
                    LDQ(qAm12, rbA, -12) LDQ(qA12, rbA, 12)
                    LD128(sAm10, rbA, -10) LD128(sA12, rbA, 12)
                    LDQ(qBm12, rbB, -12) LDQ(qB12, rbB, 12)
                    LD128(sBm10, rbB, -10) LD128(sB12, rbB, 12)
                    PCOMP2(sAm10, qAm12.y, -10, T1, T0) PCOMP2(sA12, qA12.x, 12, T1, T0)
                    PCOMP2(sBm10, qBm12.y, -10, T0, T1) PCOMP2(sB12, qB12.x, 12, T0, T1)
                }
            }
        }
#pragma unroll
        for (int m = 0; m < 26; ++m) T0[m] = T1[m];
    }
#undef PCOMP2
#undef LDQ
#undef LD128
#undef BUILD_T

    // ---- write fp16x4 partials {R,G,B,W} to ws ----
#pragma unroll
    for (int rr = 0; rr < 2; ++rr) {
        uint2 p0, p1, p2, p3;
        {
            hh4 h; h.x = (_Float16)aR[rr][0]; h.y = (_Float16)aG[rr][0];
                   h.z = (_Float16)aB[rr][0]; h.w = (_Float16)aW[rr][0];
            p0 = __builtin_bit_cast(uint2, h);
        }
        { hh4 h; h.x = (_Float16)aR[rr][1]; h.y = (_Float16)aG[rr][1];
                 h.z = (_Float16)aB[rr][1]; h.w = (_Float16)aW[rr][1];
            p1 = __builtin_bit_cast(uint2, h); }
        { hh4 h; h.x = (_Float16)aR[rr][2]; h.y = (_Float16)aG[rr][2];
                 h.z = (_Float16)aB[rr][2]; h.w = (_Float16)aW[rr][2];
            p2 = __builtin_bit_cast(uint2, h); }
        { hh4 h; h.x = (_Float16)aR[rr][3]; h.y = (_Float16)aG[rr][3];
                 h.z = (_Float16)aB[rr][3]; h.w = (_Float16)aW[rr][3];
            p3 = __builtin_bit_cast(uint2, h); }
        uint4 w01, w23;
        w01.x = p0.x; w01.y = p0.y; w01.z = p1.x; w01.w = p1.y;
        w23.x = p2.x; w23.y = p2.y; w23.z = p3.x; w23.w = p3.y;
        const size_t wbase = (size_t)(bb * 3 + l) * HWSZ
                           + (size_t)(by0 + 2 * ty + rr) * WW + (size_t)(bx0 + 4 * tx);
        *reinterpret_cast<uint4*>(ws + wbase)     = w01;
        *reinterpret_cast<uint4*>(ws + wbase + 2) = w23;
    }
}

// ---------------------------------------------------------------------------
// Kernel 2: front-to-back compositing, elementwise over B*H*W pixels.
// ---------------------------------------------------------------------------
__global__ __launch_bounds__(256, 4)
void mlr_comp_kernel(const uint2* __restrict__ ws, float* __restrict__ out)
{
    const int p = blockIdx.x * 256 + threadIdx.x;   // 0 .. B*HWSZ-1
    const int b = p >> 18;                          // HWSZ = 2^18
    const int i = p & (HWSZ - 1);

    float blurR = 0.f, blurG = 0.f, blurB = 0.f, trans = 1.f;
#pragma unroll
    for (int l = 0; l < 3; ++l) {
        const uint2 v = ws[(size_t)(b * 3 + l) * HWSZ + i];
        const hh4 h = __builtin_bit_cast(hh4, v);
        const float wsum = (float)h.w;
        const float occ  = clamp01(wsum);
        const float f    = trans * occ / (wsum + 1e-8f);
        blurR = fmaf((float)h.x, f, blurR);
        blurG = fmaf((float)h.y, f, blurG);
        blurB = fmaf((float)h.z, f, blurB);
        trans *= (1.0f - occ);
    }
    out[(size_t)(b * 3 + 0) * HWSZ + i] = blurR;
    out[(size_t)(b * 3 + 1) * HWSZ + i] = blurG;
    out[(size_t)(b * 3 + 2) * HWSZ + i] = blurB;
}

// ---------------------------------------------------------------------------
// Fallback (only if ws too small; R3 proved ws >= 12.6 MB on this harness):
// naive correct per-pixel gather.
// ---------------------------------------------------------------------------
__global__ __launch_bounds__(256)
void mlr_naive_kernel(const float* __restrict__ rgbad,
                      const float* __restrict__ lens_eff,
                      const float* __restrict__ focal,
                      float* __restrict__ out)
{
    static constexpr float DJ[44] = {
        0.f, 1.f, 1.41421356f, 2.f, 2.23606798f, 2.82842712f, 3.f, 3.16227766f,
        3.60555128f, 4.f, 4.12310563f, 4.24264069f, 4.47213595f, 5.f, 5.09901951f,
        5.38516481f, 5.65685425f, 5.83095189f, 6.f, 6.08276253f, 6.32455532f,
        6.40312424f, 6.70820393f, 7.f, 7.07106781f, 7.21110255f, 7.28010989f,
        7.61577311f, 7.81024968f, 8.f, 8.06225775f, 8.24621125f, 8.48528137f,
        8.54400375f, 8.60232527f, 8.94427191f, 9.f, 9.05538514f, 9.21954446f,
        9.43398113f, 9.48683298f, 9.84885780f, 9.89949494f, 10.f };
    static constexpr float CNT[44] = {
        1,4,4,4,8,4,4,8,8,4,8,4,8,12,8,8,4,8,4,8,8,8,
        8,4,12,8,8,8,8,4,16,8,4,8,8,8,4,8,16,8,8,8,4,12 };

    const int p = blockIdx.x * 256 + threadIdx.x;
    const int b = p >> 18;
    const int i = p & (HWSZ - 1);
    const int y = i >> 9, x = i & 511;
    const float lens = lens_eff[b];

    float blurR = 0.f, blurG = 0.f, blurB = 0.f, trans = 1.f;
    for (int l = 0; l < 3; ++l) {
        const float* pin = rgbad + (size_t)(b * 15 + 5 * l) * HWSZ;
        const float* pfo = focal + (size_t)(b * 15 + 5 * l) * HWSZ;
        float aR = 0.f, aG = 0.f, aB = 0.f, aW = 0.f;
        for (int oy = -10; oy <= 10; ++oy) {
            for (int ox = -10; ox <= 10; ++ox) {
                const float q = (float)(oy * oy + ox * ox);
                if (q > 100.0f) continue;
                const int sy = y + oy, sx = x + ox;
                if ((unsigned)sy >= (unsigned)HH || (unsigned)sx >= (unsigned)WW) continue;
                const int off = sy * WW + sx;
                const float cr = pin[off]          - pfo[off];
                const float cg = pin[off +   HWSZ] - pfo[off +   HWSZ];
                const float cb = pin[off + 2*HWSZ] - pfo[off + 2*HWSZ];
                const float ca = pin[off + 3*HWSZ] - pfo[off + 3*HWSZ];
                const float cd = pin[off + 4*HWSZ] - pfo[off + 4*HWSZ];
                const float r  = fminf(fabsf(cd) * lens, 10.f);
                const float rp05 = r + 0.5f;
                float area = 0.f;
                for (int j = 0; j < 44; ++j)
                    area = fmaf(CNT[j], clamp01(rp05 - DJ[j]), area);
                const float pa = ca / (area + 1e-8f);
                const float w  = clamp01(rp05 - __builtin_sqrtf(q));
                aR = fmaf(cr * pa, w, aR);
                aG = fmaf(cg * pa, w, aG);
                aB = fmaf(cb * pa, w, aB);
                aW = fmaf(pa, w, aW);
            }
        }
        const float occ = clamp01(aW);
        const float f   = trans * occ / (aW + 1e-8f);
        blurR = fmaf(aR, f, blurR);
        blurG = fmaf(aG, f, blurG);
        blurB = fmaf(aB, f, blurB);
        trans *= (1.0f - occ);
    }
    out[(size_t)(b * 3 + 0) * HWSZ + i] = blurR;
    out[(size_t)(b * 3 + 1) * HWSZ + i] = blurG;
    out[(size_t)(b * 3 + 2) * HWSZ + i] = blurB;
}

extern "C" void kernel_launch(void* const* d_in, const int* in_sizes, int n_in,
                              void* d_out, int out_size, void* d_ws, size_t ws_size,
                              hipStream_t stream) {
    const float* rgbad = (const float*)d_in[0];
    const float* lens  = (const float*)d_in[1];
    const float* focal = (const float*)d_in[2];
    float* out = (float*)d_out;
    const int B = in_sizes[1];                 // lens_effect: [B,1]

    const size_t ws_need = (size_t)B * 3 * HWSZ * sizeof(uint2);
    if (ws_size >= ws_need) {
        const int nbx = WW / TW;               // 8
        const int nby = HH / TH;               // 32
        dim3 grid1(nbx * nby * 3 * B, 1, 1);   // 1536 blocks (B=2)
        dim3 block1(16, 8, 1);                 // 128 thr: 4px x 2rows each
        hipLaunchKernelGGL(mlr_layer_kernel, grid1, block1, 0, stream,
                           rgbad, lens, focal, (uint2*)d_ws, nbx, B);
        dim3 grid2((B * HWSZ) / 256, 1, 1);
        dim3 block2(256, 1, 1);
        hipLaunchKernelGGL(mlr_comp_kernel, grid2, block2, 0, stream,
                           (const uint2*)d_ws, out);
    } else {
        dim3 grid((B * HWSZ) / 256, 1, 1);
        dim3 block(256, 1, 1);
        hipLaunchKernelGGL(mlr_naive_kernel, grid, block, 0, stream,
                           rgbad, lens, focal, out);
    }
}

// Round 14
// 45.643 us; speedup vs baseline: 1.3273x; 1.2946x over previous
//
#include <hip/hip_runtime.h>
#include <hip/hip_bf16.h>

#define HH 512
#define WW 512
#define HWSZ (512*512)

typedef _Float16 hh4 __attribute__((ext_vector_type(4)));
typedef _Float16 hh2 __attribute__((ext_vector_type(2)));
typedef float    ff4 __attribute__((ext_vector_type(4)));

constexpr int TW = 64, TH = 16;   // output tile
constexpr int SW = 88;            // staged cols bx0-12 .. bx0+75
constexpr int SH = 36;            // staged rows by0-10 .. by0+25
constexpr int LP = 92;            // stride %4==0 (b64 quads + b128 pairs aligned)
constexpr int NG = SW / 4;        // 22 groups of 4 px
constexpr int NSLOT = SH * NG;    // 792
constexpr int NIT = 4;            // 4*256 >= 792 (tail clamped)

__device__ __forceinline__ float clamp01(float x) {
    return __builtin_amdgcn_fmed3f(x, 0.0f, 1.0f);
}
__device__ __forceinline__ hh2 clamp01h2(hh2 x) {
    const hh2 z = {(_Float16)0.0f, (_Float16)0.0f};
    const hh2 o = {(_Float16)1.0f, (_Float16)1.0f};
    return __builtin_elementwise_min(__builtin_elementwise_max(x, z), o);
}
__device__ __forceinline__ hh2 pkrtz(float a, float b) {
    return __builtin_bit_cast(hh2, __builtin_amdgcn_cvt_pkrtz(a, b));
}

// ---------------------------------------------------------------------------
// Kernel 1: ONE (batch, layer) per block-slice; 4 px/thread (proven R11
// per-wave structure, verbatim gather); writes fp16x4 {R,G,B,W} to ws.
// 1536 blocks -> 16 waves/CU resident (2x the fused ceiling).
// ---------------------------------------------------------------------------
__global__ __launch_bounds__(256, 2)
void mlr_layer_kernel(const float* __restrict__ rgbad,
                      const float* __restrict__ lens_eff,
                      const float* __restrict__ focal,
                      uint2* __restrict__ ws,
                      int nbx, int B)
{
    __shared__ uint2 sP[SH * LP];       // half4 {r*pa,g*pa,b*pa,pa}  26.5 KB
    __shared__ uint  rP[SH * LP / 2];   // half2 rp05 pairs            6.6 KB
    __shared__ int   maxbits;

    const int tx  = threadIdx.x;    // 0..15 (4 px each)
    const int ty  = threadIdx.y;    // 0..15
    const int tid = ty * 16 + tx;
    const int nsl = 3 * B;          // slices (batch,layer) fastest -> balance
    const int bid = blockIdx.x;
    const int sl  = bid % nsl;
    const int bb  = sl % B;
    const int l   = sl / B;
    const int t   = bid / nsl;
    const int bx0 = (t % nbx) * TW;
    const int by0 = (t / nbx) * TH;
    const float lens = lens_eff[bb];

    static constexpr float DJ[44] = {
        0.f, 1.f, 1.41421356f, 2.f, 2.23606798f, 2.82842712f, 3.f, 3.16227766f,
        3.60555128f, 4.f, 4.12310563f, 4.24264069f, 4.47213595f, 5.f, 5.09901951f,
        5.38516481f, 5.65685425f, 5.83095189f, 6.f, 6.08276253f, 6.32455532f,
        6.40312424f, 6.70820393f, 7.f, 7.07106781f, 7.21110255f, 7.28010989f,
        7.61577311f, 7.81024968f, 8.f, 8.06225775f, 8.24621125f, 8.48528137f,
        8.54400375f, 8.60232527f, 8.94427191f, 9.f, 9.05538514f, 9.21954446f,
        9.43398113f, 9.48683298f, 9.84885780f, 9.89949494f, 10.f };
    static constexpr float CNT[44] = {
        1,4,4,4,8,4,4,8,8,4,8,4,8,12,8,8,4,8,4,8,8,8,
        8,4,12,8,8,8,8,4,16,8,4,8,8,8,4,8,16,8,8,8,4,12 };

    if (tid == 0) maxbits = 0;
    __syncthreads();

    const float* pin = rgbad + (size_t)(bb * 15 + 5 * l) * HWSZ;
    const float* pfo = focal + (size_t)(bb * 15 + 5 * l) * HWSZ;
    float mloc = 0.f;

    // ---- staging: fixed-trip loop, float4 loads (tail clamped, benign) ----
#pragma unroll
    for (int it = 0; it < NIT; ++it) {
        int s = tid + it * 256;
        s = (s < NSLOT) ? s : (NSLOT - 1);
        const int row = s / NG;
        const int grp = s - row * NG;
        const int gy  = by0 - 10 + row;
        const int gx0 = bx0 - 12 + 4 * grp;     // %4 == 0

        ff4 i0 = {0,0,0,0}, i1 = {0,0,0,0}, i2 = {0,0,0,0}, i3 = {0,0,0,0}, i4 = {0,0,0,0};
        ff4 f0 = {0,0,0,0}, f1 = {0,0,0,0}, f2 = {0,0,0,0}, f3 = {0,0,0,0}, f4 = {0,0,0,0};
        const bool valid = ((unsigned)gy < (unsigned)HH) && ((unsigned)gx0 < (unsigned)WW);
        if (valid) {
            const size_t off = (size_t)gy * WW + (size_t)gx0;
            i0 = *reinterpret_cast<const ff4*>(pin + off);
            i1 = *reinterpret_cast<const ff4*>(pin + off +   HWSZ);
            i2 = *reinterpret_cast<const ff4*>(pin + off + 2*HWSZ);
            i3 = *reinterpret_cast<const ff4*>(pin + off + 3*HWSZ);
            i4 = *reinterpret_cast<const ff4*>(pin + off + 4*HWSZ);
            f0 = *reinterpret_cast<const ff4*>(pfo + off);
            f1 = *reinterpret_cast<const ff4*>(pfo + off +   HWSZ);
            f2 = *reinterpret_cast<const ff4*>(pfo + off + 2*HWSZ);
            f3 = *reinterpret_cast<const ff4*>(pfo + off + 3*HWSZ);
            f4 = *reinterpret_cast<const ff4*>(pfo + off + 4*HWSZ);
        }
        uint2 pk[4];
        unsigned short rh[4];
#pragma unroll
        for (int k = 0; k < 4; ++k) {
            const float cr = i0[k] - f0[k];
            const float cg = i1[k] - f1[k];
            const float cb = i2[k] - f2[k];
            const float ca = i3[k] - f3[k];
            const float cd = i4[k] - f4[k];
            const float r  = fminf(fabsf(cd) * lens, 10.f);
            const float rp05 = r + 0.5f;
            const hh2 rp2s = pkrtz(rp05, rp05);
            float aacc = 0.f;
#pragma unroll
            for (int j = 0; j < 44; j += 2) {
                const hh2 dj2 = {(_Float16)DJ[j], (_Float16)DJ[j + 1]};
                const hh2 c2  = {(_Float16)CNT[j], (_Float16)CNT[j + 1]};
                const hh2 w2  = clamp01h2(rp2s - dj2);
                aacc = __builtin_amdgcn_fdot2(w2, c2, aacc, false);
            }
            const float inv = 1.0f / (aacc + 1e-8f);
            const float pa  = ca * inv;          // 0 when OOB (loads were 0)
            hh4 hv;
            hv.x = (_Float16)(cr * pa);
            hv.y = (_Float16)(cg * pa);
            hv.z = (_Float16)(cb * pa);
            hv.w = (_Float16)pa;
            pk[k] = __builtin_bit_cast(uint2, hv);
            rh[k] = __builtin_bit_cast(unsigned short, (_Float16)rp05);
            mloc  = fmaxf(mloc, rp05);           // 0.5 for OOB px: harmless
        }
        const int base = row * LP + 4 * grp;     // %4 == 0
        uint4 s01, s23;
        s01.x = pk[0].x; s01.y = pk[0].y; s01.z = pk[1].x; s01.w = pk[1].y;
        s23.x = pk[2].x; s23.y = pk[2].y; s23.z = pk[3].x; s23.w = pk[3].y;
        *reinterpret_cast<uint4*>(&sP[base])     = s01;
        *reinterpret_cast<uint4*>(&sP[base + 2]) = s23;
        uint2 rr2;
        rr2.x = (uint)rh[0] | ((uint)rh[1] << 16);
        rr2.y = (uint)rh[2] | ((uint)rh[3] << 16);
        *reinterpret_cast<uint2*>(&rP[base >> 1]) = rr2;
    }
    atomicMax(&maxbits, __float_as_int(mloc));
    __syncthreads();

    const float rmax = __int_as_float(maxbits);   // block-uniform
    const int U = min(10, (int)ceilf(rmax) - 1);

    float accR[4] = {0,0,0,0}, accG[4] = {0,0,0,0};
    float accB[4] = {0,0,0,0}, accW[4] = {0,0,0,0};

#define PCOMP(SP_, RPH_, v0) { \
        const hh2 rp2 = __builtin_bit_cast(hh2, (RPH_)); \
        const hh2 cR = __builtin_bit_cast(hh2, __builtin_amdgcn_perm((SP_).z, (SP_).x, 0x05040100u)); \
        const hh2 cG = __builtin_bit_cast(hh2, __builtin_amdgcn_perm((SP_).z, (SP_).x, 0x07060302u)); \
        const hh2 cB = __builtin_bit_cast(hh2, __builtin_amdgcn_perm((SP_).w, (SP_).y, 0x05040100u)); \
        const hh2 cA = __builtin_bit_cast(hh2, __builtin_amdgcn_perm((SP_).w, (SP_).y, 0x07060302u)); \
        _Pragma("unroll") \
        for (int ox = 0; ox < 4; ++ox) { \
            const hh2 w2 = clamp01h2(rp2 - hdd2[(v0) - ox + 13]); \
            accR[ox] = __builtin_amdgcn_fdot2(cR, w2, accR[ox], false); \
            accG[ox] = __builtin_amdgcn_fdot2(cG, w2, accG[ox], false); \
            accB[ox] = __builtin_amdgcn_fdot2(cB, w2, accB[ox], false); \
            accW[ox] = __builtin_amdgcn_fdot2(cA, w2, accW[ox], false); \
        } }
#define LDQ(nm, rb, off)   const uint2 nm = *reinterpret_cast<const uint2*>(&rP[((rb) + (off)) >> 1]);
#define LD128(nm, rb, off) const uint4 nm = *reinterpret_cast<const uint4*>(&sP[(rb) + (off)]);

    // ---- u = 0 row ----
    {
        hh2 hdd2[26];
#pragma unroll
        for (int m = 0; m < 26; ++m) {
            const int dxa = m - 13, dxb = dxa + 1;
            const float qa = (float)(dxa * dxa);
            const float qb = (float)(dxb * dxb);
            const float da = (qa <= 100.0f) ? __builtin_sqrtf(qa) : 3000.0f;
            const float db = (qb <= 100.0f) ? __builtin_sqrtf(qb) : 3000.0f;
            hdd2[m] = pkrtz(da, db);
        }
        const float vm2 = rmax * rmax;
        const int rbA = (ty + 10) * LP + 12 + 4 * tx;   // %4 == 0
        LDQ(qAm4, rbA, -4) LDQ(qA0, rbA, 0) LDQ(qA4, rbA, 4)
        LD128(sAm2, rbA, -2) LD128(sA0, rbA, 0) LD128(sA2, rbA, 2) LD128(sA4, rbA, 4)
        PCOMP(sAm2, qAm4.y, -2) PCOMP(sA0, qA0.x, 0) PCOMP(sA2, qA0.y, 2) PCOMP(sA4, qA4.x, 4)
        if (vm2 > 9.0f) {
            LDQ(qAm8, rbA, -8) LDQ(qA8, rbA, 8)
            LD128(sAm6, rbA, -6) LD128(sAm4, rbA, -4) LD128(sA6, rbA, 6) LD128(sA8, rbA, 8)
            PCOMP(sAm6, qAm8.y, -6) PCOMP(sAm4, qAm4.x, -4) PCOMP(sA6, qA4.y, 6) PCOMP(sA8, qA8.x, 8)
            if (vm2 > 36.0f) {
                LD128(sAm8, rbA, -8) LD128(sA10, rbA, 10)
                PCOMP(sAm8, qAm8.x, -8) PCOMP(sA10, qA8.y, 10)
                if (vm2 > 81.0f) {
                    LDQ(qAm12, rbA, -12) LDQ(qA12, rbA, 12)
                    LD128(sAm10, rbA, -10) LD128(sA12, rbA, 12)
                    PCOMP(sAm10, qAm12.y, -10) PCOMP(sA12, qA12.x, 12)
                }
            }
        }
    }

    // ---- u = +/-au row pairs (shared hdd2: d depends on u^2 only) ----
#pragma unroll 1
    for (int au = 1; au <= U; ++au) {
        const float u2f = (float)(au * au);
        const float vm2 = rmax * rmax - u2f;
        hh2 hdd2[26];
#pragma unroll
        for (int m = 0; m < 26; ++m) {
            const int dxa = m - 13, dxb = dxa + 1;
            const float qa = u2f + (float)(dxa * dxa);
            const float qb = u2f + (float)(dxb * dxb);
            const float da = (qa <= 100.0f) ? __builtin_sqrtf(qa) : 3000.0f;
            const float db = (qb <= 100.0f) ? __builtin_sqrtf(qb) : 3000.0f;
            hdd2[m] = pkrtz(da, db);
        }
        const int rbA = (ty + 10 + au) * LP + 12 + 4 * tx;
        const int rbB = (ty + 10 - au) * LP + 12 + 4 * tx;

        LDQ(qAm4, rbA, -4) LDQ(qA0, rbA, 0) LDQ(qA4, rbA, 4)
        LD128(sAm2, rbA, -2) LD128(sA0, rbA, 0) LD128(sA2, rbA, 2) LD128(sA4, rbA, 4)
        LDQ(qBm4, rbB, -4) LDQ(qB0, rbB, 0) LDQ(qB4, rbB, 4)
        LD128(sBm2, rbB, -2) LD128(sB0, rbB, 0) LD128(sB2, rbB, 2) LD128(sB4, rbB, 4)
        PCOMP(sAm2, qAm4.y, -2) PCOMP(sA0, qA0.x, 0) PCOMP(sA2, qA0.y, 2) PCOMP(sA4, qA4.x, 4)
        PCOMP(sBm2, qBm4.y, -2) PCOMP(sB0, qB0.x, 0) PCOMP(sB2, qB0.y, 2) PCOMP(sB4, qB4.x, 4)
        if (vm2 > 9.0f) {
            LDQ(qAm8, rbA, -8) LDQ(qA8, rbA, 8)
            LD128(sAm6, rbA, -6) LD128(sAm4, rbA, -4) LD128(sA6, rbA, 6) LD128(sA8, rbA, 8)
            LDQ(qBm8, rbB, -8) LDQ(qB8, rbB, 8)
            LD128(sBm6, rbB, -6) LD128(sBm4, rbB, -4) LD128(sB6, rbB, 6) LD128(sB8, rbB, 8)
            PCOMP(sAm6, qAm8.y, -6) PCOMP(sAm4, qAm4.x, -4) PCOMP(sA6, qA4.y, 6) PCOMP(sA8, qA8.x, 8)
            PCOMP(sBm6, qBm8.y, -6) PCOMP(sBm4, qBm4.x, -4) PCOMP(sB6, qB4.y, 6) PCOMP(sB8, qB8.x, 8)
            if (vm2 > 36.0f) {
                LD128(sAm8, rbA, -8) LD128(sA10, rbA, 10)
                LD128(sBm8, rbB, -8) LD128(sB10, rbB, 10)
                PCOMP(sAm8, qAm8.x, -8) PCOMP(sA10, qA8.y, 10)
                PCOMP(sBm8, qBm8.x, -8) PCOMP(sB10, qB8.y, 10)
                if (vm2 > 81.0f) {
                    LDQ(qAm12, rbA, -12) LDQ(qA12, rbA, 12)
                    LD128(sAm10, rbA, -10) LD128(sA12, rbA, 12)
                    LDQ(qBm12, rbB, -12) LDQ(qB12, rbB, 12)
                    LD128(sBm10, rbB, -10) LD128(sB12, rbB, 12)
                    PCOMP(sAm10, qAm12.y, -10) PCOMP(sA12, qA12.x, 12)
                    PCOMP(sBm10, qBm12.y, -10) PCOMP(sB12, qB12.x, 12)
                }
            }
        }
    }
#undef PCOMP
#undef LDQ
#undef LD128

    // ---- write fp16x4 partials {R,G,B,W} to ws ----
    uint2 p[4];
#pragma unroll
    for (int ox = 0; ox < 4; ++ox) {
        hh4 h;
        h.x = (_Float16)accR[ox]; h.y = (_Float16)accG[ox];
        h.z = (_Float16)accB[ox]; h.w = (_Float16)accW[ox];
        p[ox] = __builtin_bit_cast(uint2, h);
    }
    uint4 w01, w23;
    w01.x = p[0].x; w01.y = p[0].y; w01.z = p[1].x; w01.w = p[1].y;
    w23.x = p[2].x; w23.y = p[2].y; w23.z = p[3].x; w23.w = p[3].y;
    const size_t wbase = (size_t)(bb * 3 + l) * HWSZ
                       + (size_t)(by0 + ty) * WW + (size_t)(bx0 + 4 * tx);
    *reinterpret_cast<uint4*>(ws + wbase)     = w01;
    *reinterpret_cast<uint4*>(ws + wbase + 2) = w23;
}

// ---------------------------------------------------------------------------
// Kernel 2: front-to-back compositing, elementwise over B*H*W pixels.
// ---------------------------------------------------------------------------
__global__ __launch_bounds__(256, 4)
void mlr_comp_kernel(const uint2* __restrict__ ws, float* __restrict__ out)
{
    const int p = blockIdx.x * 256 + threadIdx.x;   // 0 .. B*HWSZ-1
    const int b = p >> 18;                          // HWSZ = 2^18
    const int i = p & (HWSZ - 1);

    float blurR = 0.f, blurG = 0.f, blurB = 0.f, trans = 1.f;
#pragma unroll
    for (int l = 0; l < 3; ++l) {
        const uint2 v = ws[(size_t)(b * 3 + l) * HWSZ + i];
        const hh4 h = __builtin_bit_cast(hh4, v);
        const float wsum = (float)h.w;
        const float occ  = clamp01(wsum);
        const float f    = trans * occ / (wsum + 1e-8f);
        blurR = fmaf((float)h.x, f, blurR);
        blurG = fmaf((float)h.y, f, blurG);
        blurB = fmaf((float)h.z, f, blurB);
        trans *= (1.0f - occ);
    }
    out[(size_t)(b * 3 + 0) * HWSZ + i] = blurR;
    out[(size_t)(b * 3 + 1) * HWSZ + i] = blurG;
    out[(size_t)(b * 3 + 2) * HWSZ + i] = blurB;
}

// ---------------------------------------------------------------------------
// Fallback (only if ws too small; ws >= 12.6 MB proven on this harness).
// ---------------------------------------------------------------------------
__global__ __launch_bounds__(256)
void mlr_naive_kernel(const float* __restrict__ rgbad,
                      const float* __restrict__ lens_eff,
                      const float* __restrict__ focal,
                      float* __restrict__ out)
{
    static constexpr float DJ[44] = {
        0.f, 1.f, 1.41421356f, 2.f, 2.23606798f, 2.82842712f, 3.f, 3.16227766f,
        3.60555128f, 4.f, 4.12310563f, 4.24264069f, 4.47213595f, 5.f, 5.09901951f,
        5.38516481f, 5.65685425f, 5.83095189f, 6.f, 6.08276253f, 6.32455532f,
        6.40312424f, 6.70820393f, 7.f, 7.07106781f, 7.21110255f, 7.28010989f,
        7.61577311f, 7.81024968f, 8.f, 8.06225775f, 8.24621125f, 8.48528137f,
        8.54400375f, 8.60232527f, 8.94427191f, 9.f, 9.05538514f, 9.21954446f,
        9.43398113f, 9.48683298f, 9.84885780f, 9.89949494f, 10.f };
    static constexpr float CNT[44] = {
        1,4,4,4,8,4,4,8,8,4,8,4,8,12,8,8,4,8,4,8,8,8,
        8,4,12,8,8,8,8,4,16,8,4,8,8,8,4,8,16,8,8,8,4,12 };

    const int p = blockIdx.x * 256 + threadIdx.x;
    const int b = p >> 18;
    const int i = p & (HWSZ - 1);
    const int y = i >> 9, x = i & 511;
    const float lens = lens_eff[b];

    float blurR = 0.f, blurG = 0.f, blurB = 0.f, trans = 1.f;
    for (int l = 0; l < 3; ++l) {
        const float* pin = rgbad + (size_t)(b * 15 + 5 * l) * HWSZ;
        const float* pfo = focal + (size_t)(b * 15 + 5 * l) * HWSZ;
        float aR = 0.f, aG = 0.f, aB = 0.f, aW = 0.f;
        for (int oy = -10; oy <= 10; ++oy) {
            for (int ox = -10; ox <= 10; ++ox) {
                const float q = (float)(oy * oy + ox * ox);
                if (q > 100.0f) continue;
                const int sy = y + oy, sx = x + ox;
                if ((unsigned)sy >= (unsigned)HH || (unsigned)sx >= (unsigned)WW) continue;
                const int off = sy * WW + sx;
                const float cr = pin[off]          - pfo[off];
                const float cg = pin[off +   HWSZ] - pfo[off +   HWSZ];
                const float cb = pin[off + 2*HWSZ] - pfo[off + 2*HWSZ];
                const float ca = pin[off + 3*HWSZ] - pfo[off + 3*HWSZ];
                const float cd = pin[off + 4*HWSZ] - pfo[off + 4*HWSZ];
                const float r  = fminf(fabsf(cd) * lens, 10.f);
                const float rp05 = r + 0.5f;
                float area = 0.f;
                for (int j = 0; j < 44; ++j)
                    area = fmaf(CNT[j], clamp01(rp05 - DJ[j]), area);
                const float pa = ca / (area + 1e-8f);
                const float w  = clamp01(rp05 - __builtin_sqrtf(q));
                aR = fmaf(cr * pa, w, aR);
                aG = fmaf(cg * pa, w, aG);
                aB = fmaf(cb * pa, w, aB);
                aW = fmaf(pa, w, aW);
            }
        }
        const float occ = clamp01(aW);
        const float f   = trans * occ / (aW + 1e-8f);
        blurR = fmaf(aR, f, blurR);
        blurG = fmaf(aG, f, blurG);
        blurB = fmaf(aB, f, blurB);
        trans *= (1.0f - occ);
    }
    out[(size_t)(b * 3 + 0) * HWSZ + i] = blurR;
    out[(size_t)(b * 3 + 1) * HWSZ + i] = blurG;
    out[(size_t)(b * 3 + 2) * HWSZ + i] = blurB;
}

extern "C" void kernel_launch(void* const* d_in, const int* in_sizes, int n_in,
                              void* d_out, int out_size, void* d_ws, size_t ws_size,
                              hipStream_t stream) {
    const float* rgbad = (const float*)d_in[0];
    const float* lens  = (const float*)d_in[1];
    const float* focal = (const float*)d_in[2];
    float* out = (float*)d_out;
    const int B = in_sizes[1];                 // lens_effect: [B,1]

    const size_t ws_need = (size_t)B * 3 * HWSZ * sizeof(uint2);
    if (ws_size >= ws_need) {
        const int nbx = WW / TW;               // 8
        const int nby = HH / TH;               // 32
        dim3 grid1(nbx * nby * 3 * B, 1, 1);   // 1536 blocks (B=2)
        dim3 block1(16, 16, 1);                // 256 thr, 4 px each
        hipLaunchKernelGGL(mlr_layer_kernel, grid1, block1, 0, stream,
                           rgbad, lens, focal, (uint2*)d_ws, nbx, B);
        dim3 grid2((B * HWSZ) / 256, 1, 1);
        dim3 block2(256, 1, 1);
        hipLaunchKernelGGL(mlr_comp_kernel, grid2, block2, 0, stream,
                           (const uint2*)d_ws, out);
    } else {
        dim3 grid((B * HWSZ) / 256, 1, 1);
        dim3 block(256, 1, 1);
        hipLaunchKernelGGL(mlr_naive_kernel, grid, block, 0, stream,
                           rgbad, lens, focal, out);
    }
}